// Round 4
// baseline (531.074 us; speedup 1.0000x reference)
//
#include <hip/hip_runtime.h>
#include <hip/hip_bf16.h>
#include <stdint.h>

// Problem constants
#define L_TOT 2304   // 48*48
#define D_IN  64
#define NF    32     // features per head
#define NH    8      // heads
#define NB    2      // batch
#define MW    256    // MLP width = NH*NF
#define CHS   4      // l-chunks for stats pass
#define NSTRIP (L_TOT/32)   // 72 m-strips

constexpr float EPSV  = 1e-5f;
constexpr float SCALE = 0.17677669529663687f;  // 1/sqrt(32)
constexpr float SHIFT = 20.0f;                 // softmax exp shift (s >= 0 always)

typedef __bf16  bf16x4  __attribute__((ext_vector_type(4)));
typedef __bf16  bf16x8  __attribute__((ext_vector_type(8)));
typedef float   f32x16  __attribute__((ext_vector_type(16)));

union U32x4BF { uint32_t u[4]; bf16x8 v; };

// Pack two f32 -> one u32 of two bf16 (element 0 = low halfword = a).
static __device__ __forceinline__ uint32_t pack_bf16(float a, float b) {
    union { __bf16 h[2]; uint32_t u; } r;
    r.h[0] = (__bf16)a;
    r.h[1] = (__bf16)b;
    return r.u;
}

// ---------------------------------------------------------------------------
// Kernel 1: fused projection (Q,K,V) + bias + InstanceNorm(32) + ReLU -> bf16
//   Qb [hn][l][32] (pre-scaled by 1/sqrt(32)), Kb [hn][l][32],
//   Vt [hn][strip][f][32m]  (direct bf16x4 global stores, no LDS transpose)
// block = 1024 (4 row-groups x 8h x 32f), 16 l-rows per block, grid = 288
// ---------------------------------------------------------------------------
__global__ __launch_bounds__(1024) void k_proj(
    const float* __restrict__ x,
    const float* __restrict__ Wq, const float* __restrict__ bq,
    const float* __restrict__ Wk, const float* __restrict__ bk,
    const float* __restrict__ Wv, const float* __restrict__ bv,
    __hip_bfloat16* __restrict__ Qo, __hip_bfloat16* __restrict__ Ko,
    __hip_bfloat16* __restrict__ Vt)
{
    const int tile = blockIdx.x;
    const int n  = tile / (L_TOT / 16);
    const int l0 = (tile % (L_TOT / 16)) * 16;
    const int tid = threadIdx.x;
    const int rg = tid >> 8;          // row group 0..3 (rows rg*4 .. rg*4+3)
    const int h = (tid >> 5) & 7, f = tid & 31;
    const int r0 = rg * 4;

    __shared__ float xs[16][D_IN];
    for (int i = tid; i < 16 * D_IN; i += 1024) {
        int d = i >> 4, r = i & 15;
        xs[r][d] = x[n * D_IN * L_TOT + d * L_TOT + l0 + r];
    }
    __syncthreads();

    const float* Ws[3] = {Wq, Wk, Wv};
    const float* bs[3] = {bq, bk, bv};
    const int hn = h * NB + n;
    const int strip = l0 >> 5;
    const int mbase = l0 & 31;

    #pragma unroll
    for (int mtx = 0; mtx < 3; ++mtx) {
        float acc[4] = {0.f, 0.f, 0.f, 0.f};
        const float* W = Ws[mtx] + h * D_IN * NF + f;
        for (int d = 0; d < D_IN; ++d) {
            float w = W[d * NF];
            #pragma unroll
            for (int rr = 0; rr < 4; ++rr) acc[rr] += xs[r0 + rr][d] * w;
        }
        const float bias = bs[mtx][h * NF + f];
        __bf16 vtmp[4];
        #pragma unroll
        for (int rr = 0; rr < 4; ++rr) {
            const int r = r0 + rr;
            float v = acc[rr] + bias;
            float s = v, s2 = v * v;
            #pragma unroll
            for (int o = 16; o >= 1; o >>= 1) {
                s  += __shfl_xor(s,  o, 32);
                s2 += __shfl_xor(s2, o, 32);
            }
            float mu  = s  * (1.f / 32);
            float var = s2 * (1.f / 32) - mu * mu;
            float y = fmaxf((v - mu) * rsqrtf(var + EPSV), 0.f);
            if (mtx == 0) {
                Qo[((size_t)hn * L_TOT + l0 + r) * NF + f] = __float2bfloat16(y * SCALE);
            } else if (mtx == 1) {
                Ko[((size_t)hn * L_TOT + l0 + r) * NF + f] = __float2bfloat16(y);
            } else {
                vtmp[rr] = (__bf16)y;
            }
        }
        if (mtx == 2) {
            // V^T: 4 contiguous m-values per thread -> one 8B store
            bf16x4* dst = reinterpret_cast<bf16x4*>(
                Vt + ((size_t)(hn * NSTRIP + strip) * 32 + f) * 32 + mbase + r0);
            bf16x4 vv = {vtmp[0], vtmp[1], vtmp[2], vtmp[3]};
            *dst = vv;
        }
    }
}

// ---------------------------------------------------------------------------
// Kernel 2: column softmax stats. S^T = K @ Q^T per 32-m strip via MFMA.
// Z[m] = sum_l exp(s - 20). Stored permuted: zpart[chunk][hn][strip*32 + hi*16 + r]
// block = 256 (4 indep waves), grid = (18, 16 hn, CHS)
// ---------------------------------------------------------------------------
__global__ __launch_bounds__(256) void k_stats(
    const __hip_bfloat16* __restrict__ Qb, const __hip_bfloat16* __restrict__ Kb,
    float* __restrict__ zpart)
{
    const int w = threadIdx.x >> 6;
    const int strip = blockIdx.x * 4 + w;
    const int hn = blockIdx.y;
    const int chunk = blockIdx.z;
    const int lane = threadIdx.x & 63;
    const int c = lane & 31, hi = lane >> 5;

    const bf16x8* kp = reinterpret_cast<const bf16x8*>(
        Kb + ((size_t)hn * L_TOT + strip * 32 + c) * NF);
    const bf16x8 ka0 = kp[hi];      // f 0..15 across the two half-waves
    const bf16x8 ka1 = kp[2 + hi];  // f 16..31

    float Zr[16];
    #pragma unroll
    for (int r = 0; r < 16; ++r) Zr[r] = 0.f;

    for (int it = 0; it < (L_TOT / 32) / CHS; ++it) {
        const int l0 = (chunk * ((L_TOT / 32) / CHS) + it) * 32;
        const bf16x8* qp = reinterpret_cast<const bf16x8*>(
            Qb + ((size_t)hn * L_TOT + l0 + c) * NF);
        bf16x8 qb0 = qp[hi];
        bf16x8 qb1 = qp[2 + hi];
        f32x16 s16 = {};
        s16 = __builtin_amdgcn_mfma_f32_32x32x16_bf16(ka0, qb0, s16, 0, 0, 0);
        s16 = __builtin_amdgcn_mfma_f32_32x32x16_bf16(ka1, qb1, s16, 0, 0, 0);
        #pragma unroll
        for (int r = 0; r < 16; ++r) Zr[r] += __expf(s16[r] - SHIFT);
    }
    // reduce across the 32 col-lanes of each half
    #pragma unroll
    for (int r = 0; r < 16; ++r) {
        #pragma unroll
        for (int o = 16; o >= 1; o >>= 1) Zr[r] += __shfl_xor(Zr[r], o, 64);
    }
    if (c == 0) {
        float4* zp = reinterpret_cast<float4*>(
            zpart + ((size_t)chunk * 16 + hn) * L_TOT + strip * 32 + hi * 16);
        zp[0] = make_float4(Zr[0], Zr[1], Zr[2], Zr[3]);
        zp[1] = make_float4(Zr[4], Zr[5], Zr[6], Zr[7]);
        zp[2] = make_float4(Zr[8], Zr[9], Zr[10], Zr[11]);
        zp[3] = make_float4(Zr[12], Zr[13], Zr[14], Zr[15]);
    }
}

// Combine chunks -> lse (same permuted layout)
__global__ __launch_bounds__(256) void k_finish(
    const float* __restrict__ zpart, float* __restrict__ lse_p)
{
    const int idx = blockIdx.x * 256 + threadIdx.x;  // hn*L + perm(m)
    float Z = 0.f;
    #pragma unroll
    for (int cc = 0; cc < CHS; ++cc) Z += zpart[(size_t)cc * 16 * L_TOT + idx];
    lse_p[idx] = SHIFT + logf(Z);
}

// ---------------------------------------------------------------------------
// Kernel 3: apply. Per 32-l tile: S^T tile via MFMA, p = exp(s - lse[m]),
// bit-pack + shfl_xor(32) relayout into A-fragments, PV via MFMA.
// Partial over m-chunks -> partA[chunk][n][l][h*32+f]
// block = 256 (4 indep waves), grid = (18, 16 hn, CH)
// ---------------------------------------------------------------------------
__global__ __launch_bounds__(256) void k_apply(
    const __hip_bfloat16* __restrict__ Qb, const __hip_bfloat16* __restrict__ Kb,
    const __hip_bfloat16* __restrict__ Vt, const float* __restrict__ lse_p,
    float* __restrict__ partA, int CH)
{
    const int w = threadIdx.x >> 6;
    const int ltile = blockIdx.x * 4 + w;
    const int l0 = ltile * 32;
    const int hn = blockIdx.y;
    const int chunk = blockIdx.z;
    const int lane = threadIdx.x & 63;
    const int c = lane & 31, hi = lane >> 5;

    const bf16x8* qp = reinterpret_cast<const bf16x8*>(
        Qb + ((size_t)hn * L_TOT + l0 + c) * NF);
    const bf16x8 qb0 = qp[hi];
    const bf16x8 qb1 = qp[2 + hi];

    f32x16 acc = {};
    const int nsteps = NSTRIP / CH;

    for (int it = 0; it < nsteps; ++it) {
        const int st = chunk * nsteps + it;
        // S^T tile
        const bf16x8* kp = reinterpret_cast<const bf16x8*>(
            Kb + ((size_t)hn * L_TOT + st * 32 + c) * NF);
        f32x16 s16 = {};
        s16 = __builtin_amdgcn_mfma_f32_32x32x16_bf16(kp[hi], qb0, s16, 0, 0, 0);
        s16 = __builtin_amdgcn_mfma_f32_32x32x16_bf16(kp[2 + hi], qb1, s16, 0, 0, 0);

        // lse for this lane's 16 rows (permuted layout, broadcast within half)
        const float4* lp = reinterpret_cast<const float4*>(
            lse_p + (size_t)hn * L_TOT + st * 32 + hi * 16);
        float lv[16];
        #pragma unroll
        for (int q = 0; q < 4; ++q) {
            float4 t = lp[q];
            lv[4 * q + 0] = t.x; lv[4 * q + 1] = t.y;
            lv[4 * q + 2] = t.z; lv[4 * q + 3] = t.w;
        }
        float p[16];
        #pragma unroll
        for (int r = 0; r < 16; ++r) p[r] = __expf(s16[r] - lv[r]);

        // pack to bf16 pairs: wp[q] = (row 2q, row 2q+1) of this half
        uint32_t wp[8];
        #pragma unroll
        for (int q = 0; q < 8; ++q) wp[q] = pack_bf16(p[2 * q], p[2 * q + 1]);

        // cross-half exchange: build A-fragments for PV
        uint32_t sendA = hi ? wp[0] : wp[2];
        uint32_t sendB = hi ? wp[1] : wp[3];
        uint32_t rA = (uint32_t)__shfl_xor((int)sendA, 32, 64);
        uint32_t rB = (uint32_t)__shfl_xor((int)sendB, 32, 64);
        U32x4BF fragP0;
        fragP0.u[0] = hi ? rA    : wp[0];
        fragP0.u[1] = hi ? rB    : wp[1];
        fragP0.u[2] = hi ? wp[2] : rA;
        fragP0.u[3] = hi ? wp[3] : rB;
        uint32_t sendC = hi ? wp[4] : wp[6];
        uint32_t sendD = hi ? wp[5] : wp[7];
        uint32_t rC = (uint32_t)__shfl_xor((int)sendC, 32, 64);
        uint32_t rD = (uint32_t)__shfl_xor((int)sendD, 32, 64);
        U32x4BF fragP1;
        fragP1.u[0] = hi ? rC    : wp[4];
        fragP1.u[1] = hi ? rD    : wp[5];
        fragP1.u[2] = hi ? wp[6] : rC;
        fragP1.u[3] = hi ? wp[7] : rD;

        // V B-fragments: Vt[hn][st][f=c][m]
        const bf16x8* vp = reinterpret_cast<const bf16x8*>(
            Vt + ((size_t)(hn * NSTRIP + st) * 32 + c) * 32);
        acc = __builtin_amdgcn_mfma_f32_32x32x16_bf16(fragP0.v, vp[hi], acc, 0, 0, 0);
        acc = __builtin_amdgcn_mfma_f32_32x32x16_bf16(fragP1.v, vp[2 + hi], acc, 0, 0, 0);
    }

    const int n = hn & 1, h = hn >> 1;
    float* outp = partA + (size_t)chunk * (NB * L_TOT * MW)
                + ((size_t)(n * L_TOT + l0)) * MW + h * NF + c;
    #pragma unroll
    for (int r = 0; r < 16; ++r) {
        int row = (r & 3) + 8 * (r >> 2) + 4 * hi;
        outp[(size_t)row * MW] = acc[r];
    }
}

// ---------------------------------------------------------------------------
// Kernel 4: heads = sum(partA) ; m=relu(relu(h@W1+b1)@W2+b2) ;
//           o = gamma*inorm(m+h)+beta ; out[n,c,l] (transposed store)
// block = 1024 (4 row-groups x 256 channels), 16 l-rows per block, grid = 288
// ---------------------------------------------------------------------------
__global__ __launch_bounds__(1024) void k_mlp(
    const float* __restrict__ partA,
    const float* __restrict__ W1, const float* __restrict__ b1,
    const float* __restrict__ W2, const float* __restrict__ b2,
    const float* __restrict__ gamma, const float* __restrict__ beta,
    float* __restrict__ out, int CH)
{
    const int tile = blockIdx.x;
    const int n  = tile / (L_TOT / 16);
    const int l0 = (tile % (L_TOT / 16)) * 16;
    const int tid = threadIdx.x;
    const int c = tid & 255;
    const int rg = tid >> 8;            // row group 0..3
    const int r0 = rg * 4;
    const int wid = (tid >> 6) & 3;     // c-quarter within row group
    const int lane = tid & 63;

    __shared__ float hs[16][MW];
    __shared__ float ms[16][MW];

    for (int idx = tid; idx < 16 * MW; idx += 1024) {
        int r = idx >> 8, i = idx & 255;
        float v = 0.f;
        for (int k = 0; k < CH; ++k)
            v += partA[(size_t)k * (NB * L_TOT * MW) + ((size_t)n * L_TOT + l0 + r) * MW + i];
        hs[r][i] = v;
    }
    __syncthreads();

    float acc[4] = {0.f, 0.f, 0.f, 0.f};
    for (int i = 0; i < MW; i += 4) {
        float w0 = W1[(i + 0) * MW + c];
        float w1 = W1[(i + 1) * MW + c];
        float w2 = W1[(i + 2) * MW + c];
        float w3 = W1[(i + 3) * MW + c];
        #pragma unroll
        for (int rr = 0; rr < 4; ++rr) {
            const float4 h4 = *(const float4*)&hs[r0 + rr][i];
            acc[rr] += h4.x * w0 + h4.y * w1 + h4.z * w2 + h4.w * w3;
        }
    }
    {
        const float bb = b1[c];
        #pragma unroll
        for (int rr = 0; rr < 4; ++rr) ms[r0 + rr][c] = fmaxf(acc[rr] + bb, 0.f);
    }
    __syncthreads();

    #pragma unroll
    for (int rr = 0; rr < 4; ++rr) acc[rr] = 0.f;
    for (int i = 0; i < MW; i += 4) {
        float w0 = W2[(i + 0) * MW + c];
        float w1 = W2[(i + 1) * MW + c];
        float w2 = W2[(i + 2) * MW + c];
        float w3 = W2[(i + 3) * MW + c];
        #pragma unroll
        for (int rr = 0; rr < 4; ++rr) {
            const float4 h4 = *(const float4*)&ms[r0 + rr][i];
            acc[rr] += h4.x * w0 + h4.y * w1 + h4.z * w2 + h4.w * w3;
        }
    }

    float y[4];
    {
        const float bb = b2[c];
        #pragma unroll
        for (int rr = 0; rr < 4; ++rr) y[rr] = fmaxf(acc[rr] + bb, 0.f) + hs[r0 + rr][c];
    }

    __shared__ float rs[16][4], rs2[16][4];
    #pragma unroll
    for (int rr = 0; rr < 4; ++rr) {
        float s = y[rr], s2 = y[rr] * y[rr];
        #pragma unroll
        for (int o = 32; o >= 1; o >>= 1) { s += __shfl_xor(s, o, 64); s2 += __shfl_xor(s2, o, 64); }
        if (lane == 0) { rs[r0 + rr][wid] = s; rs2[r0 + rr][wid] = s2; }
    }
    __syncthreads();

    const float g = gamma[c], be = beta[c];
    float ov[4];
    #pragma unroll
    for (int rr = 0; rr < 4; ++rr) {
        const int r = r0 + rr;
        float s  = rs[r][0]  + rs[r][1]  + rs[r][2]  + rs[r][3];
        float s2 = rs2[r][0] + rs2[r][1] + rs2[r][2] + rs2[r][3];
        float mu  = s  * (1.f / MW);
        float var = s2 * (1.f / MW) - mu * mu;
        float o = (y[rr] - mu) * rsqrtf(var + EPSV);
        ov[rr] = g * o + be;
    }
    float4* op = (float4*)&out[((size_t)n * MW + c) * L_TOT + l0 + r0];
    *op = make_float4(ov[0], ov[1], ov[2], ov[3]);
}

// ---------------------------------------------------------------------------
extern "C" void kernel_launch(void* const* d_in, const int* in_sizes, int n_in,
                              void* d_out, int out_size, void* d_ws, size_t ws_size,
                              hipStream_t stream) {
    const float* x  = (const float*)d_in[0];
    const float* Wq = (const float*)d_in[1];
    const float* bq = (const float*)d_in[2];
    const float* Wk = (const float*)d_in[3];
    const float* bk = (const float*)d_in[4];
    const float* Wv = (const float*)d_in[5];
    const float* bv = (const float*)d_in[6];
    const float* W1 = (const float*)d_in[7];
    const float* b1 = (const float*)d_in[8];
    const float* W2 = (const float*)d_in[9];
    const float* b2 = (const float*)d_in[10];
    const float* gm = (const float*)d_in[11];
    const float* bt = (const float*)d_in[12];
    float* out = (float*)d_out;

    const size_t QKVE = (size_t)16 * L_TOT * NF;         // 1,179,648 bf16 elems
    const size_t BF_BYTES = 3 * QKVE * sizeof(__hip_bfloat16);  // 7,077,888
    const size_t ZN = (size_t)CHS * 16 * L_TOT;          // zpart floats
    const size_t LN = (size_t)16 * L_TOT;                // lse floats
    const size_t HEADS = (size_t)NB * L_TOT * MW;        // partA floats per chunk

    __hip_bfloat16* Qb = (__hip_bfloat16*)d_ws;
    __hip_bfloat16* Kb = Qb + QKVE;
    __hip_bfloat16* Vt = Kb + QKVE;
    float* zpart = (float*)((char*)d_ws + BF_BYTES);
    float* lse_p = zpart + ZN;
    float* partA = lse_p + LN;

    const size_t fixed = BF_BYTES + (ZN + LN) * sizeof(float);
    int CH = 1;
    for (int cc = 4; cc >= 2; cc >>= 1) {
        if (fixed + (size_t)cc * HEADS * sizeof(float) <= ws_size) { CH = cc; break; }
    }

    k_proj<<<dim3(NB * (L_TOT / 16)), dim3(1024), 0, stream>>>(
        x, Wq, bq, Wk, bk, Wv, bv, Qb, Kb, Vt);
    k_stats<<<dim3(NSTRIP / 4, 16, CHS), dim3(256), 0, stream>>>(Qb, Kb, zpart);
    k_finish<<<dim3(16 * L_TOT / 256), dim3(256), 0, stream>>>(zpart, lse_p);
    k_apply<<<dim3(NSTRIP / 4, 16, CH), dim3(256), 0, stream>>>(
        Qb, Kb, Vt, lse_p, partA, CH);
    k_mlp<<<dim3(NB * (L_TOT / 16)), dim3(1024), 0, stream>>>(
        partA, W1, b1, W2, b2, gm, bt, out, CH);
}

// Round 5
// 137.451 us; speedup vs baseline: 3.8637x; 3.8637x over previous
//
#include <hip/hip_runtime.h>
#include <hip/hip_bf16.h>
#include <stdint.h>

// Problem constants
#define L_TOT 2304   // 48*48
#define D_IN  64
#define NF    32     // features per head
#define NH    8      // heads
#define NB    2      // batch
#define MW    256    // MLP width = NH*NF
#define CHS   4      // l-chunks for stats pass
#define NSTRIP (L_TOT/32)   // 72 m-strips
#define RT    32     // rows per k_mlp block

constexpr float EPSV  = 1e-5f;
constexpr float SCALE = 0.17677669529663687f;  // 1/sqrt(32)
constexpr float SHIFT = 20.0f;                 // softmax exp shift (s >= 0 always)

typedef __bf16  bf16x4  __attribute__((ext_vector_type(4)));
typedef __bf16  bf16x8  __attribute__((ext_vector_type(8)));
typedef float   f32x16  __attribute__((ext_vector_type(16)));

union U32x4BF { uint32_t u[4]; bf16x8 v; };

// Pack two f32 -> one u32 of two bf16 (element 0 = low halfword = a).
static __device__ __forceinline__ uint32_t pack_bf16(float a, float b) {
    union { __bf16 h[2]; uint32_t u; } r;
    r.h[0] = (__bf16)a;
    r.h[1] = (__bf16)b;
    return r.u;
}

// ---------------------------------------------------------------------------
// Kernel 0: transpose W1,W2 -> bf16 [out][in] for MFMA B-operands
// grid (8,8,2), block (32,8)
// ---------------------------------------------------------------------------
__global__ void k_prep(const float* __restrict__ W1, const float* __restrict__ W2,
                       __hip_bfloat16* __restrict__ W1t, __hip_bfloat16* __restrict__ W2t)
{
    const float* src = blockIdx.z ? W2 : W1;
    __hip_bfloat16* dst = blockIdx.z ? W2t : W1t;
    __shared__ float t[32][33];
    const int bi = blockIdx.x * 32, bj = blockIdx.y * 32;
    #pragma unroll
    for (int k = 0; k < 4; ++k)
        t[threadIdx.y + 8*k][threadIdx.x] = src[(size_t)(bi + threadIdx.y + 8*k) * MW + bj + threadIdx.x];
    __syncthreads();
    #pragma unroll
    for (int k = 0; k < 4; ++k)
        dst[(size_t)(bj + threadIdx.y + 8*k) * MW + bi + threadIdx.x] =
            __float2bfloat16(t[threadIdx.x][threadIdx.y + 8*k]);
}

// ---------------------------------------------------------------------------
// Kernel 1: fused projection (Q,K,V) + bias + InstanceNorm(32) + ReLU -> bf16
// Weights staged in LDS once per block (kills the R4 L2-miss storm).
// block = 1024 (4 row-groups x 8h x 32f), 16 l-rows per block, grid = 288
// ---------------------------------------------------------------------------
__global__ __launch_bounds__(1024) void k_proj(
    const float* __restrict__ x,
    const float* __restrict__ Wq, const float* __restrict__ bq,
    const float* __restrict__ Wk, const float* __restrict__ bk,
    const float* __restrict__ Wv, const float* __restrict__ bv,
    __hip_bfloat16* __restrict__ Qo, __hip_bfloat16* __restrict__ Ko,
    __hip_bfloat16* __restrict__ Vt)
{
    const int tile = blockIdx.x;
    const int n  = tile / (L_TOT / 16);
    const int l0 = (tile % (L_TOT / 16)) * 16;
    const int tid = threadIdx.x;
    const int rg = tid >> 8;          // row group 0..3 (rows rg*4 .. rg*4+3)
    const int h = (tid >> 5) & 7, f = tid & 31;
    const int r0 = rg * 4;

    __shared__ float xs[16][D_IN];
    __shared__ float Wl[D_IN * MW];   // 64 KB staged weights (layout [h][d][f])

    for (int i = tid; i < 16 * D_IN; i += 1024) {
        int d = i >> 4, r = i & 15;
        xs[r][d] = x[n * D_IN * L_TOT + d * L_TOT + l0 + r];
    }

    const float* Ws[3] = {Wq, Wk, Wv};
    const float* bs[3] = {bq, bk, bv};
    const int hn = h * NB + n;
    const int strip = l0 >> 5;
    const int mbase = l0 & 31;

    #pragma unroll
    for (int mtx = 0; mtx < 3; ++mtx) {
        __syncthreads();   // protect Wl readers of previous mtx (and xs on first pass)
        {
            const float4* srcW = reinterpret_cast<const float4*>(Ws[mtx]);
            float4* dstW = reinterpret_cast<float4*>(Wl);
            #pragma unroll
            for (int i = 0; i < 4; ++i) dstW[tid + i * 1024] = srcW[tid + i * 1024];
        }
        __syncthreads();

        float acc[4] = {0.f, 0.f, 0.f, 0.f};
        const float* wp = Wl + h * (D_IN * NF) + f;
        for (int d = 0; d < D_IN; ++d) {
            float wv = wp[d * NF];
            #pragma unroll
            for (int rr = 0; rr < 4; ++rr) acc[rr] += xs[r0 + rr][d] * wv;
        }
        const float bias = bs[mtx][h * NF + f];
        __bf16 vtmp[4];
        #pragma unroll
        for (int rr = 0; rr < 4; ++rr) {
            const int r = r0 + rr;
            float v = acc[rr] + bias;
            float s = v, s2 = v * v;
            #pragma unroll
            for (int o = 16; o >= 1; o >>= 1) {
                s  += __shfl_xor(s,  o, 32);
                s2 += __shfl_xor(s2, o, 32);
            }
            float mu  = s  * (1.f / 32);
            float var = s2 * (1.f / 32) - mu * mu;
            float y = fmaxf((v - mu) * rsqrtf(var + EPSV), 0.f);
            if (mtx == 0) {
                Qo[((size_t)hn * L_TOT + l0 + r) * NF + f] = __float2bfloat16(y * SCALE);
            } else if (mtx == 1) {
                Ko[((size_t)hn * L_TOT + l0 + r) * NF + f] = __float2bfloat16(y);
            } else {
                vtmp[rr] = (__bf16)y;
            }
        }
        if (mtx == 2) {
            bf16x4* dst = reinterpret_cast<bf16x4*>(
                Vt + ((size_t)(hn * NSTRIP + strip) * 32 + f) * 32 + mbase + r0);
            bf16x4 vv = {vtmp[0], vtmp[1], vtmp[2], vtmp[3]};
            *dst = vv;
        }
    }
}

// ---------------------------------------------------------------------------
// Kernel 2: column softmax stats. S^T = K @ Q^T per 32-m strip via MFMA.
// Z[m] = sum_l exp(s - 20). Stored permuted: zpart[chunk][hn][strip*32 + hi*16 + r]
// block = 256 (4 indep waves), grid = (18, 16 hn, CHS)
// ---------------------------------------------------------------------------
__global__ __launch_bounds__(256) void k_stats(
    const __hip_bfloat16* __restrict__ Qb, const __hip_bfloat16* __restrict__ Kb,
    float* __restrict__ zpart)
{
    const int w = threadIdx.x >> 6;
    const int strip = blockIdx.x * 4 + w;
    const int hn = blockIdx.y;
    const int chunk = blockIdx.z;
    const int lane = threadIdx.x & 63;
    const int c = lane & 31, hi = lane >> 5;

    const bf16x8* kp = reinterpret_cast<const bf16x8*>(
        Kb + ((size_t)hn * L_TOT + strip * 32 + c) * NF);
    const bf16x8 ka0 = kp[hi];      // f 0..15 across the two half-waves
    const bf16x8 ka1 = kp[2 + hi];  // f 16..31

    float Zr[16];
    #pragma unroll
    for (int r = 0; r < 16; ++r) Zr[r] = 0.f;

    for (int it = 0; it < (L_TOT / 32) / CHS; ++it) {
        const int l0 = (chunk * ((L_TOT / 32) / CHS) + it) * 32;
        const bf16x8* qp = reinterpret_cast<const bf16x8*>(
            Qb + ((size_t)hn * L_TOT + l0 + c) * NF);
        bf16x8 qb0 = qp[hi];
        bf16x8 qb1 = qp[2 + hi];
        f32x16 s16 = {};
        s16 = __builtin_amdgcn_mfma_f32_32x32x16_bf16(ka0, qb0, s16, 0, 0, 0);
        s16 = __builtin_amdgcn_mfma_f32_32x32x16_bf16(ka1, qb1, s16, 0, 0, 0);
        #pragma unroll
        for (int r = 0; r < 16; ++r) Zr[r] += __expf(s16[r] - SHIFT);
    }
    #pragma unroll
    for (int r = 0; r < 16; ++r) {
        #pragma unroll
        for (int o = 16; o >= 1; o >>= 1) Zr[r] += __shfl_xor(Zr[r], o, 64);
    }
    if (c == 0) {
        float4* zp = reinterpret_cast<float4*>(
            zpart + ((size_t)chunk * 16 + hn) * L_TOT + strip * 32 + hi * 16);
        zp[0] = make_float4(Zr[0], Zr[1], Zr[2], Zr[3]);
        zp[1] = make_float4(Zr[4], Zr[5], Zr[6], Zr[7]);
        zp[2] = make_float4(Zr[8], Zr[9], Zr[10], Zr[11]);
        zp[3] = make_float4(Zr[12], Zr[13], Zr[14], Zr[15]);
    }
}

// Combine chunks -> lse (same permuted layout)
__global__ __launch_bounds__(256) void k_finish(
    const float* __restrict__ zpart, float* __restrict__ lse_p)
{
    const int idx = blockIdx.x * 256 + threadIdx.x;
    float Z = 0.f;
    #pragma unroll
    for (int cc = 0; cc < CHS; ++cc) Z += zpart[(size_t)cc * 16 * L_TOT + idx];
    lse_p[idx] = SHIFT + logf(Z);
}

// ---------------------------------------------------------------------------
// Kernel 3: apply. S^T via MFMA, p = exp(s - lse[m]), relayout, PV via MFMA.
// block = 256 (4 indep waves), grid = (18, 16 hn, CH)
// ---------------------------------------------------------------------------
__global__ __launch_bounds__(256) void k_apply(
    const __hip_bfloat16* __restrict__ Qb, const __hip_bfloat16* __restrict__ Kb,
    const __hip_bfloat16* __restrict__ Vt, const float* __restrict__ lse_p,
    float* __restrict__ partA, int CH)
{
    const int w = threadIdx.x >> 6;
    const int ltile = blockIdx.x * 4 + w;
    const int l0 = ltile * 32;
    const int hn = blockIdx.y;
    const int chunk = blockIdx.z;
    const int lane = threadIdx.x & 63;
    const int c = lane & 31, hi = lane >> 5;

    const bf16x8* qp = reinterpret_cast<const bf16x8*>(
        Qb + ((size_t)hn * L_TOT + l0 + c) * NF);
    const bf16x8 qb0 = qp[hi];
    const bf16x8 qb1 = qp[2 + hi];

    f32x16 acc = {};
    const int nsteps = NSTRIP / CH;

    for (int it = 0; it < nsteps; ++it) {
        const int st = chunk * nsteps + it;
        const bf16x8* kp = reinterpret_cast<const bf16x8*>(
            Kb + ((size_t)hn * L_TOT + st * 32 + c) * NF);
        f32x16 s16 = {};
        s16 = __builtin_amdgcn_mfma_f32_32x32x16_bf16(kp[hi], qb0, s16, 0, 0, 0);
        s16 = __builtin_amdgcn_mfma_f32_32x32x16_bf16(kp[2 + hi], qb1, s16, 0, 0, 0);

        const float4* lp = reinterpret_cast<const float4*>(
            lse_p + (size_t)hn * L_TOT + st * 32 + hi * 16);
        float lv[16];
        #pragma unroll
        for (int q = 0; q < 4; ++q) {
            float4 t = lp[q];
            lv[4 * q + 0] = t.x; lv[4 * q + 1] = t.y;
            lv[4 * q + 2] = t.z; lv[4 * q + 3] = t.w;
        }
        float p[16];
        #pragma unroll
        for (int r = 0; r < 16; ++r) p[r] = __expf(s16[r] - lv[r]);

        uint32_t wp[8];
        #pragma unroll
        for (int q = 0; q < 8; ++q) wp[q] = pack_bf16(p[2 * q], p[2 * q + 1]);

        uint32_t sendA = hi ? wp[0] : wp[2];
        uint32_t sendB = hi ? wp[1] : wp[3];
        uint32_t rA = (uint32_t)__shfl_xor((int)sendA, 32, 64);
        uint32_t rB = (uint32_t)__shfl_xor((int)sendB, 32, 64);
        U32x4BF fragP0;
        fragP0.u[0] = hi ? rA    : wp[0];
        fragP0.u[1] = hi ? rB    : wp[1];
        fragP0.u[2] = hi ? wp[2] : rA;
        fragP0.u[3] = hi ? wp[3] : rB;
        uint32_t sendC = hi ? wp[4] : wp[6];
        uint32_t sendD = hi ? wp[5] : wp[7];
        uint32_t rC = (uint32_t)__shfl_xor((int)sendC, 32, 64);
        uint32_t rD = (uint32_t)__shfl_xor((int)sendD, 32, 64);
        U32x4BF fragP1;
        fragP1.u[0] = hi ? rC    : wp[4];
        fragP1.u[1] = hi ? rD    : wp[5];
        fragP1.u[2] = hi ? wp[6] : rC;
        fragP1.u[3] = hi ? wp[7] : rD;

        const bf16x8* vp = reinterpret_cast<const bf16x8*>(
            Vt + ((size_t)(hn * NSTRIP + st) * 32 + c) * 32);
        acc = __builtin_amdgcn_mfma_f32_32x32x16_bf16(fragP0.v, vp[hi], acc, 0, 0, 0);
        acc = __builtin_amdgcn_mfma_f32_32x32x16_bf16(fragP1.v, vp[2 + hi], acc, 0, 0, 0);
    }

    const int n = hn & 1, h = hn >> 1;
    float* outp = partA + (size_t)chunk * (NB * L_TOT * MW)
                + ((size_t)(n * L_TOT + l0)) * MW + h * NF + c;
    #pragma unroll
    for (int r = 0; r < 16; ++r) {
        int row = (r & 3) + 8 * (r >> 2) + 4 * hi;
        outp[(size_t)row * MW] = acc[r];
    }
}

// ---------------------------------------------------------------------------
// Kernel 4 (MFMA MLP): heads = sum(partA); m=relu(relu(h@W1+b1)@W2+b2);
//   o = gamma*inorm(m+h)+beta; out[n,c,l].
// block = 512 (8 waves x 32-col groups), 32 rows/block, grid = 144
// ---------------------------------------------------------------------------
__global__ __launch_bounds__(512) void k_mlp(
    const float* __restrict__ partA,
    const __hip_bfloat16* __restrict__ W1t, const float* __restrict__ b1,
    const __hip_bfloat16* __restrict__ W2t, const float* __restrict__ b2,
    const float* __restrict__ gamma, const float* __restrict__ beta,
    float* __restrict__ out, int CH)
{
    const int blk = blockIdx.x;
    const int n  = blk / (L_TOT / RT);
    const int l0 = (blk % (L_TOT / RT)) * RT;
    const int tid = threadIdx.x;
    const int w = tid >> 6, lane = tid & 63;
    const int c = lane & 31, hi = lane >> 5;
    const int n0 = w * 32;

    // smem map: hsf f32[32][256] @0 (32768); hA bf16[32][264] @32768 (16896);
    // msb bf16[32][264] @49664 (16896); ys f32[32][256] overlays @32768;
    // rs @66560, rs2 @67072. total 67584 B.
    __shared__ __align__(16) char smem[67584];
    float (*hsf)[MW] = reinterpret_cast<float (*)[MW]>(smem);
    __hip_bfloat16 (*hA)[264]  = reinterpret_cast<__hip_bfloat16 (*)[264]>(smem + 32768);
    __hip_bfloat16 (*msb)[264] = reinterpret_cast<__hip_bfloat16 (*)[264]>(smem + 49664);
    float (*ys)[MW] = reinterpret_cast<float (*)[MW]>(smem + 32768);
    float (*rs)[4]  = reinterpret_cast<float (*)[4]>(smem + 66560);
    float (*rs2)[4] = reinterpret_cast<float (*)[4]>(smem + 67072);

    // heads = sum over chunks -> hsf (f32 residual) + hA (bf16 MFMA A)
    for (int idx = tid; idx < RT * MW; idx += 512) {
        int r = idx >> 8, i = idx & 255;
        float v = 0.f;
        for (int k = 0; k < CH; ++k)
            v += partA[(size_t)k * (NB * L_TOT * MW) + ((size_t)n * L_TOT + l0 + r) * MW + i];
        hsf[r][i] = v;
        hA[r][i] = __float2bfloat16(v);
    }
    __syncthreads();

    // ---- layer 1: m1 = relu(h @ W1 + b1) ----
    const float bb1 = b1[n0 + c];
    bf16x8 B1[16];
    #pragma unroll
    for (int k0 = 0; k0 < 16; ++k0)
        B1[k0] = *reinterpret_cast<const bf16x8*>(W1t + (size_t)(n0 + c) * MW + k0 * 16 + hi * 8);
    f32x16 acc = {};
    #pragma unroll
    for (int k0 = 0; k0 < 16; ++k0) {
        bf16x8 a = *reinterpret_cast<const bf16x8*>(&hA[c][k0 * 16 + hi * 8]);
        acc = __builtin_amdgcn_mfma_f32_32x32x16_bf16(a, B1[k0], acc, 0, 0, 0);
    }
    #pragma unroll
    for (int r = 0; r < 16; ++r) {
        int row = (r & 3) + 8 * (r >> 2) + 4 * hi;
        msb[row][n0 + c] = __float2bfloat16(fmaxf(acc[r] + bb1, 0.f));
    }
    __syncthreads();

    // ---- layer 2: y = relu(m1 @ W2 + b2) + h ----
    const float bb2 = b2[n0 + c];
    bf16x8 B2[16];
    #pragma unroll
    for (int k0 = 0; k0 < 16; ++k0)
        B2[k0] = *reinterpret_cast<const bf16x8*>(W2t + (size_t)(n0 + c) * MW + k0 * 16 + hi * 8);
    f32x16 acc2 = {};
    #pragma unroll
    for (int k0 = 0; k0 < 16; ++k0) {
        bf16x8 a = *reinterpret_cast<const bf16x8*>(&msb[c][k0 * 16 + hi * 8]);
        acc2 = __builtin_amdgcn_mfma_f32_32x32x16_bf16(a, B2[k0], acc2, 0, 0, 0);
    }
    float yv[16];
    #pragma unroll
    for (int r = 0; r < 16; ++r) {
        int row = (r & 3) + 8 * (r >> 2) + 4 * hi;
        yv[r] = fmaxf(acc2[r] + bb2, 0.f) + hsf[row][n0 + c];
    }
    __syncthreads();   // msb/hA dead; ys overlay safe
    #pragma unroll
    for (int r = 0; r < 16; ++r) {
        int row = (r & 3) + 8 * (r >> 2) + 4 * hi;
        ys[row][n0 + c] = yv[r];
    }
    __syncthreads();

    // ---- instance norm over 256 channels per row + transposed store ----
    const int col = tid & 255;
    const int half = tid >> 8;
    const int wid = (tid >> 6) & 3;
    float vv[16];
    #pragma unroll
    for (int r = 0; r < 16; ++r) {
        float v = ys[half * 16 + r][col];
        vv[r] = v;
        float s = v, s2 = v * v;
        #pragma unroll
        for (int o = 32; o >= 1; o >>= 1) { s += __shfl_xor(s, o, 64); s2 += __shfl_xor(s2, o, 64); }
        if (lane == 0) { rs[half * 16 + r][wid] = s; rs2[half * 16 + r][wid] = s2; }
    }
    __syncthreads();
    const float g = gamma[col], be = beta[col];
    float ov[16];
    #pragma unroll
    for (int r = 0; r < 16; ++r) {
        int row = half * 16 + r;
        float s  = rs[row][0]  + rs[row][1]  + rs[row][2]  + rs[row][3];
        float s2 = rs2[row][0] + rs2[row][1] + rs2[row][2] + rs2[row][3];
        float mu  = s  * (1.f / MW);
        float var = s2 * (1.f / MW) - mu * mu;
        ov[r] = g * ((vv[r] - mu) * rsqrtf(var + EPSV)) + be;
    }
    float* ob = out + ((size_t)n * MW + col) * L_TOT + l0 + half * 16;
    #pragma unroll
    for (int q = 0; q < 4; ++q)
        reinterpret_cast<float4*>(ob)[q] =
            make_float4(ov[4 * q], ov[4 * q + 1], ov[4 * q + 2], ov[4 * q + 3]);
}

// ---------------------------------------------------------------------------
extern "C" void kernel_launch(void* const* d_in, const int* in_sizes, int n_in,
                              void* d_out, int out_size, void* d_ws, size_t ws_size,
                              hipStream_t stream) {
    const float* x  = (const float*)d_in[0];
    const float* Wq = (const float*)d_in[1];
    const float* bq = (const float*)d_in[2];
    const float* Wk = (const float*)d_in[3];
    const float* bk = (const float*)d_in[4];
    const float* Wv = (const float*)d_in[5];
    const float* bv = (const float*)d_in[6];
    const float* W1 = (const float*)d_in[7];
    const float* b1 = (const float*)d_in[8];
    const float* W2 = (const float*)d_in[9];
    const float* b2 = (const float*)d_in[10];
    const float* gm = (const float*)d_in[11];
    const float* bt = (const float*)d_in[12];
    float* out = (float*)d_out;

    const size_t QKVE = (size_t)16 * L_TOT * NF;                 // bf16 elems each
    const size_t BF_BYTES = 3 * QKVE * sizeof(__hip_bfloat16);   // 7,077,888
    const size_t ZN = (size_t)CHS * 16 * L_TOT;
    const size_t LN = (size_t)16 * L_TOT;
    const size_t WTE = (size_t)MW * MW;                          // 65,536 per matrix
    const size_t HEADS = (size_t)NB * L_TOT * MW;                // partA floats per chunk

    __hip_bfloat16* Qb = (__hip_bfloat16*)d_ws;
    __hip_bfloat16* Kb = Qb + QKVE;
    __hip_bfloat16* Vt = Kb + QKVE;
    float* zpart = (float*)((char*)d_ws + BF_BYTES);
    float* lse_p = zpart + ZN;
    __hip_bfloat16* W1t = (__hip_bfloat16*)(lse_p + LN);
    __hip_bfloat16* W2t = W1t + WTE;
    float* partA = (float*)(W2t + WTE);

    const size_t fixed = BF_BYTES + (ZN + LN) * sizeof(float) + 2 * WTE * sizeof(__hip_bfloat16);
    int CH = 1;
    for (int cc = 4; cc >= 2; cc >>= 1) {
        if (fixed + (size_t)cc * HEADS * sizeof(float) <= ws_size) { CH = cc; break; }
    }

    k_prep<<<dim3(8, 8, 2), dim3(32, 8), 0, stream>>>(W1, W2, W1t, W2t);
    k_proj<<<dim3(NB * (L_TOT / 16)), dim3(1024), 0, stream>>>(
        x, Wq, bq, Wk, bk, Wv, bv, Qb, Kb, Vt);
    k_stats<<<dim3(NSTRIP / 4, 16, CHS), dim3(256), 0, stream>>>(Qb, Kb, zpart);
    k_finish<<<dim3(16 * L_TOT / 256), dim3(256), 0, stream>>>(zpart, lse_p);
    k_apply<<<dim3(NSTRIP / 4, 16, CH), dim3(256), 0, stream>>>(
        Qb, Kb, Vt, lse_p, partA, CH);
    k_mlp<<<dim3(NB * (L_TOT / RT)), dim3(512), 0, stream>>>(
        partA, W1t, b1, W2t, b2, gm, bt, out, CH);
}